// Round 4
// baseline (1034.131 us; speedup 1.0000x reference)
//
#include <hip/hip_runtime.h>

// Problem constants (match reference setup_inputs)
#define NB    50000   // nodes
#define BB    64      // batch  (== wavefront size: lane = b)
#define DD    16      // neighbors per node
#define NDRVN 1000    // driver nodes

// ---------------------------------------------------------------------------
// Force a (uniform) value into a VGPR (one v_mov from SGPR).  Measured: v_fma
// with an SGPR broadcast operand issues at ~half the all-VGPR rate on gfx950,
// and each weight is reused WOUT times, so one mov amortizes to ~0.2 cyc/use.
__device__ __forceinline__ float vg(float s) {
    asm("" : "+v"(s));
    return s;
}

// ---------------------------------------------------------------------------
// Transpose x (B,N) -> z0 (N,B).
__global__ __launch_bounds__(256) void transpose_kernel(
    const float* __restrict__ x, float* __restrict__ xT)
{
    int tid = blockIdx.x * 256 + threadIdx.x;   // tid = n*64 + b
    int n = tid >> 6;
    int b = tid & 63;
    if (n < NB) xT[tid] = x[b * NB + n];
}

// ---------------------------------------------------------------------------
// One 5->5 conv1x3+relu layer, ONE node per wave, scalar v_fma_f32.
// Intrinsic FMAs only: the compiler interleaves the 5 independent channel
// accumulator chains to hide dep latency (rounds 1/3 proved inline-asm FMAs
// defeat the scheduler).  x-outer / channel-inner: in-columns die as
// out-columns are produced, keeping data liveness ~70 floats (VGPR=88 in R2).
template<int WIN>
__device__ __forceinline__ void conv5(const float (&in)[5][14], float (&out)[5][14],
                                      const float* __restrict__ w,
                                      const float* __restrict__ b)
{
    constexpr int WOUT = WIN - 2;
    float wr[75];
#pragma unroll
    for (int t = 0; t < 75; ++t) wr[t] = vg(w[t]);
    float bb[5];
#pragma unroll
    for (int c = 0; c < 5; ++c) bb[c] = vg(b[c]);

#pragma unroll
    for (int x = 0; x < WOUT; ++x) {
#pragma unroll
        for (int c = 0; c < 5; ++c) {
            // bias folded into the first fma's addend: no acc-init mov
            float acc = fmaf(wr[c * 15 + 0], in[0][x + 0], bb[c]);
            acc = fmaf(wr[c * 15 + 1], in[0][x + 1], acc);
            acc = fmaf(wr[c * 15 + 2], in[0][x + 2], acc);
#pragma unroll
            for (int ci = 1; ci < 5; ++ci) {
                acc = fmaf(wr[c * 15 + ci * 3 + 0], in[ci][x + 0], acc);
                acc = fmaf(wr[c * 15 + ci * 3 + 1], in[ci][x + 1], acc);
                acc = fmaf(wr[c * 15 + ci * 3 + 2], in[ci][x + 2], acc);
            }
            out[c][x] = fmaxf(acc, 0.0f);
        }
    }
}

// ---------------------------------------------------------------------------
// One full pass, ONE node per wave, scalar f32 FMA chains.
// 1024-thread blocks (16 waves): occupancy has been pinned at ~2 blocks/CU
// (~22%) in every previous round regardless of VGPR count, so pack 16 waves
// into ONE block to force 4 waves/SIMD co-residency.  __launch_bounds__(1024)
// also hard-caps VGPR at 128; this code needs only ~88 (measured R2).
__global__ __launch_bounds__(1024)
void pass_kernel(
    const float* __restrict__ zin, float* __restrict__ zout,
    const int*  __restrict__ nidx,
    const float* __restrict__ w0, const float* __restrict__ b0,
    const float* __restrict__ w1, const float* __restrict__ b1,
    const float* __restrict__ w2, const float* __restrict__ b2,
    const float* __restrict__ w3, const float* __restrict__ b3,
    const float* __restrict__ w4, const float* __restrict__ b4,
    const float* __restrict__ w5, const float* __restrict__ b5,
    const float* __restrict__ w6, const float* __restrict__ b6)
{
    int lane = threadIdx.x & 63;
    int wv   = blockIdx.x * 16 + (threadIdx.x >> 6);  // 50000 waves, 1 node each
    int n    = __builtin_amdgcn_readfirstlane(wv);

    // Neighbor indices: 16 contiguous ints, uniform -> s_load_dwordx16.
    const int* ip = nidx + n * DD;

    // Gather this node's neighborhood (rows of 256B, perfectly coalesced).
    float g[16];
#pragma unroll
    for (int d = 0; d < 16; ++d)
        g[d] = zin[(size_t)ip[d] * BB + lane];

    float ha[5][14], hb[5][14];

    // Layer 0: 1 -> 5 channels, width 16 -> 14
    // (weight staging s_loads/movs overlap the gather's vmcnt wait)
    {
        float wr[15], bb[5];
#pragma unroll
        for (int t = 0; t < 15; ++t) wr[t] = vg(w0[t]);
#pragma unroll
        for (int c = 0; c < 5; ++c) bb[c] = vg(b0[c]);
#pragma unroll
        for (int x = 0; x < 14; ++x) {
#pragma unroll
            for (int c = 0; c < 5; ++c) {
                float acc = fmaf(wr[c * 3 + 0], g[x + 0], bb[c]);
                acc = fmaf(wr[c * 3 + 1], g[x + 1], acc);
                acc = fmaf(wr[c * 3 + 2], g[x + 2], acc);
                ha[c][x] = fmaxf(acc, 0.0f);
            }
        }
    }

    conv5<14>(ha, hb, w1, b1);   // 14 -> 12
    conv5<12>(hb, ha, w2, b2);   // 12 -> 10
    conv5<10>(ha, hb, w3, b3);   // 10 -> 8
    conv5<8> (hb, ha, w4, b4);   // 8  -> 6
    conv5<6> (ha, hb, w5, b5);   // 6  -> 4

    // Layer 6: 5 -> 1, width 4 -> 2, then pair-average.
    {
        float wr[15];
#pragma unroll
        for (int t = 0; t < 15; ++t) wr[t] = vg(w6[t]);
        float bias = vg(b6[0]);

        float t0 = fmaf(wr[0], hb[0][0], bias);
        float t1 = fmaf(wr[0], hb[0][1], bias);
        t0 = fmaf(wr[1], hb[0][1], t0);
        t0 = fmaf(wr[2], hb[0][2], t0);
        t1 = fmaf(wr[1], hb[0][2], t1);
        t1 = fmaf(wr[2], hb[0][3], t1);
#pragma unroll
        for (int ci = 1; ci < 5; ++ci) {
#pragma unroll
            for (int t = 0; t < 3; ++t) {
                t0 = fmaf(wr[ci * 3 + t], hb[ci][0 + t], t0);
                t1 = fmaf(wr[ci * 3 + t], hb[ci][1 + t], t1);
            }
        }
        t0 = fmaxf(t0, 0.0f);
        t1 = fmaxf(t1, 0.0f);
        zout[(size_t)n * BB + lane] = 0.5f * (t0 + t1);
    }
}

// ---------------------------------------------------------------------------
// Final driver gather: out[b, i] = z[driver_idx[i], b]   (out is (B, NDRV))
__global__ __launch_bounds__(256) void gather_out_kernel(
    const float* __restrict__ z, const int* __restrict__ didx,
    float* __restrict__ out)
{
    int i = blockIdx.x * 256 + threadIdx.x;
    if (i >= BB * NDRVN) return;
    int b = i / NDRVN;
    int k = i - b * NDRVN;
    out[i] = z[(size_t)didx[k] * BB + b];
}

// ---------------------------------------------------------------------------
extern "C" void kernel_launch(void* const* d_in, const int* in_sizes, int n_in,
                              void* d_out, int out_size, void* d_ws, size_t ws_size,
                              hipStream_t stream)
{
    const float* x    = (const float*)d_in[0];
    const int*   nidx = (const int*)  d_in[1];
    const int*   didx = (const int*)  d_in[2];
    const float* w[7];
    const float* b[7];
    for (int i = 0; i < 7; ++i) {
        w[i] = (const float*)d_in[3 + 2 * i];
        b[i] = (const float*)d_in[4 + 2 * i];
    }

    // Workspace: two ping-pong z buffers in (N, B) layout, 12.8 MB each.
    float* z0 = (float*)d_ws;
    float* z1 = z0 + (size_t)NB * BB;

    const int tblocks = (NB * BB) / 256;   // 12500 (transpose)
    const int pblocks = NB / 16;           // 3125: 16 waves x 1 node, 1024 thr

    transpose_kernel<<<tblocks, 256, 0, stream>>>(x, z0);

    pass_kernel<<<pblocks, 1024, 0, stream>>>(z0, z1, nidx,
        w[0], b[0], w[1], b[1], w[2], b[2], w[3], b[3],
        w[4], b[4], w[5], b[5], w[6], b[6]);
    pass_kernel<<<pblocks, 1024, 0, stream>>>(z1, z0, nidx,
        w[0], b[0], w[1], b[1], w[2], b[2], w[3], b[3],
        w[4], b[4], w[5], b[5], w[6], b[6]);
    pass_kernel<<<pblocks, 1024, 0, stream>>>(z0, z1, nidx,
        w[0], b[0], w[1], b[1], w[2], b[2], w[3], b[3],
        w[4], b[4], w[5], b[5], w[6], b[6]);
    pass_kernel<<<pblocks, 1024, 0, stream>>>(z1, z0, nidx,
        w[0], b[0], w[1], b[1], w[2], b[2], w[3], b[3],
        w[4], b[4], w[5], b[5], w[6], b[6]);

    gather_out_kernel<<<(BB * NDRVN + 255) / 256, 256, 0, stream>>>(z0, didx, (float*)d_out);
}

// Round 5
// 933.559 us; speedup vs baseline: 1.1077x; 1.1077x over previous
//
#include <hip/hip_runtime.h>

// Problem constants (match reference setup_inputs)
#define NB    50000   // nodes
#define BB    64      // batch  (== wavefront size: lane = b)
#define DD    16      // neighbors per node
#define NDRVN 1000    // driver nodes

typedef float f2 __attribute__((ext_vector_type(2)));

// ---------------------------------------------------------------------------
// Force a (uniform) value into a VGPR (one v_mov from SGPR).
__device__ __forceinline__ float vg(float s) {
    asm("" : "+v"(s));
    return s;
}
// Pack two uniform floats (from s_loads) into one f2 VGPR pair: 2 v_movs.
// 76 pairs per 5x5 layer -- weights stay packed, 1 VGPR per weight (R3
// measured 124 VGPR total, zero spills, with this staging).
__device__ __forceinline__ f2 pack2(float lo, float hi) {
    f2 r;
    r.x = vg(lo);
    r.y = vg(hi);
    return r;
}

// relu on a packed pair -> v_pk_max_f32
__device__ __forceinline__ f2 relu2(f2 a) {
    return __builtin_elementwise_max(a, (f2)0.0f);
}

// ---------------------------------------------------------------------------
// op_sel broadcast via INTRINSICS, not inline asm.
// Rounds 1/3 proved inline-asm fma chains serialize at dep latency (~8 cyc)
// because the scheduler keeps INLINEASM in source order: 3240 x 8 = 25.9k
// cyc/wave == the measured 301-315 us.  Splat-shuffles of one half of a
// packed pair are pattern-matched by AMDGPU ISel into VOP3P op_sel on
// v_pk_fma_f32; the compiler is then free to interleave the 5 independent
// channel accumulator chains (like R0, which ran at issue rate).
__device__ __forceinline__ f2 lo2(f2 w) { return __builtin_shufflevector(w, w, 0, 0); }
__device__ __forceinline__ f2 hi2(f2 w) { return __builtin_shufflevector(w, w, 1, 1); }

// j is a compile-time constant after full unrolling -> select folds away.
__device__ __forceinline__ void cstep(const f2* wp, int j, f2 in, f2& acc) {
    f2 ws = (j & 1) ? hi2(wp[j >> 1]) : lo2(wp[j >> 1]);
    acc = __builtin_elementwise_fma(ws, in, acc);
}
// first tap: bias (selected half of packed bias pair) as the addend --
// no acc-init mov.
__device__ __forceinline__ f2 cbegin(const f2* wp, int jw, const f2* bp,
                                     int jb, f2 in) {
    f2 ws = (jw & 1) ? hi2(wp[jw >> 1]) : lo2(wp[jw >> 1]);
    f2 bs = (jb & 1) ? hi2(bp[jb >> 1]) : lo2(bp[jb >> 1]);
    return __builtin_elementwise_fma(ws, in, bs);
}

// ---------------------------------------------------------------------------
// Weight staging: uniform derefs -> s_load batches (scalar L1 hot), then
// explicit v_mov pairs into packed f2 VGPRs.  Proven path (R3: clean, no
// stalls attributable to staging).
__device__ __forceinline__ void load_w75(const float* __restrict__ w,
                                         const float* __restrict__ b,
                                         f2 (&wp)[38], f2 (&bp)[3]) {
#pragma unroll
    for (int i = 0; i < 37; ++i) wp[i] = pack2(w[2 * i], w[2 * i + 1]);
    wp[37] = pack2(w[74], 0.0f);
    bp[0] = pack2(b[0], b[1]);
    bp[1] = pack2(b[2], b[3]);
    bp[2] = pack2(b[4], 0.0f);
}

__device__ __forceinline__ void load_w15(const float* __restrict__ w,
                                         const float* __restrict__ b, int nb,
                                         f2 (&wp)[8], f2 (&bp)[3]) {
#pragma unroll
    for (int i = 0; i < 7; ++i) wp[i] = pack2(w[2 * i], w[2 * i + 1]);
    wp[7] = pack2(w[14], 0.0f);
    if (nb == 5) {
        bp[0] = pack2(b[0], b[1]);
        bp[1] = pack2(b[2], b[3]);
        bp[2] = pack2(b[4], 0.0f);
    } else {
        bp[0] = pack2(b[0], 0.0f);
        bp[1] = (f2)0.0f;
        bp[2] = (f2)0.0f;
    }
}

// ---------------------------------------------------------------------------
// Transpose x (B,N) -> z0 (N,B).
__global__ __launch_bounds__(256) void transpose_kernel(
    const float* __restrict__ x, float* __restrict__ xT)
{
    int tid = blockIdx.x * 256 + threadIdx.x;   // tid = n*64 + b
    int n = tid >> 6;
    int b = tid & 63;
    if (n < NB) xT[tid] = x[b * NB + n];
}

// ---------------------------------------------------------------------------
// One 5->5 conv1x3+relu layer for TWO nodes packed as f2 (.x=node A, .y=B).
// x-outer / channel-inner: in-columns die as out-columns are produced.
template<int WIN>
__device__ __forceinline__ void conv5p(const f2 (&in)[5][14], f2 (&out)[5][14],
                                       const f2 (&wp)[38], const f2 (&bp)[3])
{
    constexpr int WOUT = WIN - 2;
#pragma unroll
    for (int x = 0; x < WOUT; ++x) {
#pragma unroll
        for (int c = 0; c < 5; ++c) {
            const int j0 = c * 15;      // parity folds at compile time
            f2 acc = cbegin(wp, j0, bp, c, in[0][x]);
            cstep(wp, j0 + 1, in[0][x + 1], acc);
            cstep(wp, j0 + 2, in[0][x + 2], acc);
#pragma unroll
            for (int ci = 1; ci < 5; ++ci) {
#pragma unroll
                for (int t = 0; t < 3; ++t)
                    cstep(wp, j0 + ci * 3 + t, in[ci][x + t], acc);
            }
            out[c][x] = relu2(acc);
        }
    }
}

// ---------------------------------------------------------------------------
// One full pass, TWO nodes per wave packed into f2 lanes.
// waves_per_eu(2,8): 256-VGPR budget; R3 measured natural liveness of this
// structure at 124 VGPR with zero spills.
__global__ __launch_bounds__(256)
__attribute__((amdgpu_waves_per_eu(2, 8)))
void pass_kernel(
    const float* __restrict__ zin, float* __restrict__ zout,
    const int*  __restrict__ nidx,
    const float* __restrict__ w0, const float* __restrict__ b0,
    const float* __restrict__ w1, const float* __restrict__ b1,
    const float* __restrict__ w2, const float* __restrict__ b2,
    const float* __restrict__ w3, const float* __restrict__ b3,
    const float* __restrict__ w4, const float* __restrict__ b4,
    const float* __restrict__ w5, const float* __restrict__ b5,
    const float* __restrict__ w6, const float* __restrict__ b6)
{
    int lane   = threadIdx.x & 63;
    int waveid = blockIdx.x * 4 + (threadIdx.x >> 6);     // 25000 waves
    int n0 = __builtin_amdgcn_readfirstlane(waveid * 2);  // nodes n0, n0+1

    // Neighbor indices for both nodes: 32 contiguous ints -> s_loads.
    const int* ip = nidx + n0 * DD;

    // Gather both nodes' neighborhoods into f2 pairs (.x = A, .y = B).
    f2 g[16];
#pragma unroll
    for (int d = 0; d < 16; ++d) {
        float a = zin[(size_t)ip[d]      * BB + lane];
        float b = zin[(size_t)ip[16 + d] * BB + lane];
        g[d] = (f2){a, b};
    }

    f2 ha[5][14], hb[5][14];

    // Layer 0: 1 -> 5 channels, width 16 -> 14
    // (weight staging s_loads/movs overlap the gather's vmcnt wait)
    {
        f2 wp[8], bp[3];
        load_w15(w0, b0, 5, wp, bp);
#pragma unroll
        for (int x = 0; x < 14; ++x) {
#pragma unroll
            for (int c = 0; c < 5; ++c) {
                const int j0 = c * 3;
                f2 acc = cbegin(wp, j0, bp, c, g[x]);
                cstep(wp, j0 + 1, g[x + 1], acc);
                cstep(wp, j0 + 2, g[x + 2], acc);
                ha[c][x] = relu2(acc);
            }
        }
    }

    { f2 wp[38], bp[3]; load_w75(w1, b1, wp, bp); conv5p<14>(ha, hb, wp, bp); }
    { f2 wp[38], bp[3]; load_w75(w2, b2, wp, bp); conv5p<12>(hb, ha, wp, bp); }
    { f2 wp[38], bp[3]; load_w75(w3, b3, wp, bp); conv5p<10>(ha, hb, wp, bp); }
    { f2 wp[38], bp[3]; load_w75(w4, b4, wp, bp); conv5p<8> (hb, ha, wp, bp); }
    { f2 wp[38], bp[3]; load_w75(w5, b5, wp, bp); conv5p<6> (ha, hb, wp, bp); }

    // Layer 6: 5 -> 1, width 4 -> 2, then pair-average.
    {
        f2 wp[8], bp[3];
        load_w15(w6, b6, 1, wp, bp);
        f2 t0 = cbegin(wp, 0, bp, 0, hb[0][0]);
        f2 t1 = cbegin(wp, 0, bp, 0, hb[0][1]);
        cstep(wp, 1, hb[0][1], t0);
        cstep(wp, 2, hb[0][2], t0);
        cstep(wp, 1, hb[0][2], t1);
        cstep(wp, 2, hb[0][3], t1);
#pragma unroll
        for (int ci = 1; ci < 5; ++ci) {
#pragma unroll
            for (int t = 0; t < 3; ++t) {
                cstep(wp, ci * 3 + t, hb[ci][0 + t], t0);
                cstep(wp, ci * 3 + t, hb[ci][1 + t], t1);
            }
        }
        t0 = relu2(t0);
        t1 = relu2(t1);
        f2 o = (t0 + t1) * 0.5f;
        zout[(size_t)n0 * BB + lane]       = o.x;
        zout[(size_t)(n0 + 1) * BB + lane] = o.y;
    }
}

// ---------------------------------------------------------------------------
// Final driver gather: out[b, i] = z[driver_idx[i], b]   (out is (B, NDRV))
__global__ __launch_bounds__(256) void gather_out_kernel(
    const float* __restrict__ z, const int* __restrict__ didx,
    float* __restrict__ out)
{
    int i = blockIdx.x * 256 + threadIdx.x;
    if (i >= BB * NDRVN) return;
    int b = i / NDRVN;
    int k = i - b * NDRVN;
    out[i] = z[(size_t)didx[k] * BB + b];
}

// ---------------------------------------------------------------------------
extern "C" void kernel_launch(void* const* d_in, const int* in_sizes, int n_in,
                              void* d_out, int out_size, void* d_ws, size_t ws_size,
                              hipStream_t stream)
{
    const float* x    = (const float*)d_in[0];
    const int*   nidx = (const int*)  d_in[1];
    const int*   didx = (const int*)  d_in[2];
    const float* w[7];
    const float* b[7];
    for (int i = 0; i < 7; ++i) {
        w[i] = (const float*)d_in[3 + 2 * i];
        b[i] = (const float*)d_in[4 + 2 * i];
    }

    // Workspace: two ping-pong z buffers in (N, B) layout, 12.8 MB each.
    float* z0 = (float*)d_ws;
    float* z1 = z0 + (size_t)NB * BB;

    const int tblocks = (NB * BB) / 256;   // 12500 (transpose)
    const int pblocks = NB / 8;            // 6250: 4 waves x 2 nodes

    transpose_kernel<<<tblocks, 256, 0, stream>>>(x, z0);

    pass_kernel<<<pblocks, 256, 0, stream>>>(z0, z1, nidx,
        w[0], b[0], w[1], b[1], w[2], b[2], w[3], b[3],
        w[4], b[4], w[5], b[5], w[6], b[6]);
    pass_kernel<<<pblocks, 256, 0, stream>>>(z1, z0, nidx,
        w[0], b[0], w[1], b[1], w[2], b[2], w[3], b[3],
        w[4], b[4], w[5], b[5], w[6], b[6]);
    pass_kernel<<<pblocks, 256, 0, stream>>>(z0, z1, nidx,
        w[0], b[0], w[1], b[1], w[2], b[2], w[3], b[3],
        w[4], b[4], w[5], b[5], w[6], b[6]);
    pass_kernel<<<pblocks, 256, 0, stream>>>(z1, z0, nidx,
        w[0], b[0], w[1], b[1], w[2], b[2], w[3], b[3],
        w[4], b[4], w[5], b[5], w[6], b[6]);

    gather_out_kernel<<<(BB * NDRVN + 255) / 256, 256, 0, stream>>>(z0, didx, (float*)d_out);
}

// Round 6
// 927.373 us; speedup vs baseline: 1.1151x; 1.0067x over previous
//
#include <hip/hip_runtime.h>

// Problem constants (match reference setup_inputs)
#define NB    50000   // nodes
#define BB    64      // batch  (== wavefront size: lane = b)
#define DD    16      // neighbors per node
#define NDRVN 1000    // driver nodes

typedef float f2 __attribute__((ext_vector_type(2)));

// ---------------------------------------------------------------------------
// relu on a packed pair -> v_pk_max_f32
__device__ __forceinline__ f2 relu2(f2 a) {
    return __builtin_elementwise_max(a, (f2)0.0f);
}
__device__ __forceinline__ f2 pfma(f2 a, f2 b, f2 c) {
    return __builtin_elementwise_fma(a, b, c);   // -> v_pk_fma_f32
}

// ---------------------------------------------------------------------------
// LDS weight layout (f2 slots; each slot holds one weight DUPLICATED [w,w],
// written once per block).  Reading a slot with ds_read_b64 at a uniform
// address materializes a splat pair with ZERO VALU instructions -- R5's
// post-mortem showed ~5k cyc/wave (~26% of VALU time) was splat/pack movs.
//   L0: w 0..14,   b 15..19
//   Li (i=1..5): w 20+80(i-1) .. +74,  b .. +79
//   L6: w 420..434, b 435
#define LW_SLOTS 436

// ---------------------------------------------------------------------------
// Transpose x (B,N) -> z0 (N,B).
__global__ __launch_bounds__(256) void transpose_kernel(
    const float* __restrict__ x, float* __restrict__ xT)
{
    int tid = blockIdx.x * 256 + threadIdx.x;   // tid = n*64 + b
    int n = tid >> 6;
    int b = tid & 63;
    if (n < NB) xT[tid] = x[b * NB + n];
}

// ---------------------------------------------------------------------------
// One 5->5 conv1x3+relu layer for TWO nodes packed as f2 (.x=node A, .y=B).
// Weights come from LDS as pre-splatted pairs: ws[j] = {w[j], w[j]}.
// x-outer / channel-inner: in-columns die as out-columns are produced.
template<int WIN>
__device__ __forceinline__ void conv5p(const f2 (&in)[5][14], f2 (&out)[5][14],
                                       const f2* lw2, int base)
{
    constexpr int WOUT = WIN - 2;
    f2 ws[75], bs[5];
#pragma unroll
    for (int t = 0; t < 75; ++t) ws[t] = lw2[base + t];       // ds_read_b64
#pragma unroll
    for (int c = 0; c < 5; ++c) bs[c] = lw2[base + 75 + c];

#pragma unroll
    for (int x = 0; x < WOUT; ++x) {
#pragma unroll
        for (int c = 0; c < 5; ++c) {
            // bias pair as the first fma's addend: no acc-init mov
            f2 acc = pfma(ws[c * 15 + 0], in[0][x + 0], bs[c]);
            acc = pfma(ws[c * 15 + 1], in[0][x + 1], acc);
            acc = pfma(ws[c * 15 + 2], in[0][x + 2], acc);
#pragma unroll
            for (int ci = 1; ci < 5; ++ci) {
                acc = pfma(ws[c * 15 + ci * 3 + 0], in[ci][x + 0], acc);
                acc = pfma(ws[c * 15 + ci * 3 + 1], in[ci][x + 1], acc);
                acc = pfma(ws[c * 15 + ci * 3 + 2], in[ci][x + 2], acc);
            }
            out[c][x] = relu2(acc);
        }
    }
}

// ---------------------------------------------------------------------------
// One full pass, TWO nodes per wave packed into f2 lanes.
// waves_per_eu(2,8) reproduces R5's winning regime: compiler picks ~128 VGPR
// with a benign ~4-slot spill (measured: 1 KB/wave scratch, negligible).
__global__ __launch_bounds__(256)
__attribute__((amdgpu_waves_per_eu(2, 8)))
void pass_kernel(
    const float* __restrict__ zin, float* __restrict__ zout,
    const int*  __restrict__ nidx,
    const float* __restrict__ w0, const float* __restrict__ b0,
    const float* __restrict__ w1, const float* __restrict__ b1,
    const float* __restrict__ w2, const float* __restrict__ b2,
    const float* __restrict__ w3, const float* __restrict__ b3,
    const float* __restrict__ w4, const float* __restrict__ b4,
    const float* __restrict__ w5, const float* __restrict__ b5,
    const float* __restrict__ w6, const float* __restrict__ b6)
{
    __shared__ f2 lw2[LW_SLOTS];

    int tid  = threadIdx.x;
    int lane = tid & 63;

    // ---- Stage weights into LDS, duplicated [v,v] per slot (cold path) ----
    {
        float* lwf = (float*)lw2;
#pragma unroll
        for (int r = 0; r < 2; ++r) {
            int idx = tid + r * 256;
            if (idx < LW_SLOTS) {
                float v;
                if      (idx <  15) v = w0[idx];
                else if (idx <  20) v = b0[idx - 15];
                else if (idx <  95) v = w1[idx - 20];
                else if (idx < 100) v = b1[idx - 95];
                else if (idx < 175) v = w2[idx - 100];
                else if (idx < 180) v = b2[idx - 175];
                else if (idx < 255) v = w3[idx - 180];
                else if (idx < 260) v = b3[idx - 255];
                else if (idx < 335) v = w4[idx - 260];
                else if (idx < 340) v = b4[idx - 335];
                else if (idx < 415) v = w5[idx - 340];
                else if (idx < 420) v = b5[idx - 415];
                else if (idx < 435) v = w6[idx - 420];
                else                v = b6[0];
                lwf[2 * idx]     = v;
                lwf[2 * idx + 1] = v;
            }
        }
    }
    __syncthreads();

    int waveid = blockIdx.x * 4 + (tid >> 6);             // 25000 waves
    int n0 = __builtin_amdgcn_readfirstlane(waveid * 2);  // nodes n0, n0+1

    // Neighbor indices for both nodes: 32 contiguous ints -> s_loads.
    const int* ip = nidx + n0 * DD;

    // Gather both nodes' neighborhoods into f2 pairs (.x = A, .y = B).
    f2 g[16];
#pragma unroll
    for (int d = 0; d < 16; ++d) {
        float a = zin[(size_t)ip[d]      * BB + lane];
        float b = zin[(size_t)ip[16 + d] * BB + lane];
        g[d] = (f2){a, b};
    }

    f2 ha[5][14], hb[5][14];

    // Layer 0: 1 -> 5 channels, width 16 -> 14
    {
        f2 ws[15], bs[5];
#pragma unroll
        for (int t = 0; t < 15; ++t) ws[t] = lw2[t];
#pragma unroll
        for (int c = 0; c < 5; ++c) bs[c] = lw2[15 + c];
#pragma unroll
        for (int x = 0; x < 14; ++x) {
#pragma unroll
            for (int c = 0; c < 5; ++c) {
                f2 acc = pfma(ws[c * 3 + 0], g[x + 0], bs[c]);
                acc = pfma(ws[c * 3 + 1], g[x + 1], acc);
                acc = pfma(ws[c * 3 + 2], g[x + 2], acc);
                ha[c][x] = relu2(acc);
            }
        }
    }

    conv5p<14>(ha, hb, lw2,  20);   // 14 -> 12
    conv5p<12>(hb, ha, lw2, 100);   // 12 -> 10
    conv5p<10>(ha, hb, lw2, 180);   // 10 -> 8
    conv5p<8> (hb, ha, lw2, 260);   // 8  -> 6
    conv5p<6> (ha, hb, lw2, 340);   // 6  -> 4

    // Layer 6: 5 -> 1, width 4 -> 2, then pair-average.
    {
        f2 ws[15];
#pragma unroll
        for (int t = 0; t < 15; ++t) ws[t] = lw2[420 + t];
        f2 bias = lw2[435];

        f2 t0 = pfma(ws[0], hb[0][0], bias);
        f2 t1 = pfma(ws[0], hb[0][1], bias);
        t0 = pfma(ws[1], hb[0][1], t0);
        t0 = pfma(ws[2], hb[0][2], t0);
        t1 = pfma(ws[1], hb[0][2], t1);
        t1 = pfma(ws[2], hb[0][3], t1);
#pragma unroll
        for (int ci = 1; ci < 5; ++ci) {
#pragma unroll
            for (int t = 0; t < 3; ++t) {
                t0 = pfma(ws[ci * 3 + t], hb[ci][0 + t], t0);
                t1 = pfma(ws[ci * 3 + t], hb[ci][1 + t], t1);
            }
        }
        t0 = relu2(t0);
        t1 = relu2(t1);
        f2 o = (t0 + t1) * 0.5f;
        zout[(size_t)n0 * BB + lane]       = o.x;
        zout[(size_t)(n0 + 1) * BB + lane] = o.y;
    }
}

// ---------------------------------------------------------------------------
// Final driver gather: out[b, i] = z[driver_idx[i], b]   (out is (B, NDRV))
__global__ __launch_bounds__(256) void gather_out_kernel(
    const float* __restrict__ z, const int* __restrict__ didx,
    float* __restrict__ out)
{
    int i = blockIdx.x * 256 + threadIdx.x;
    if (i >= BB * NDRVN) return;
    int b = i / NDRVN;
    int k = i - b * NDRVN;
    out[i] = z[(size_t)didx[k] * BB + b];
}

// ---------------------------------------------------------------------------
extern "C" void kernel_launch(void* const* d_in, const int* in_sizes, int n_in,
                              void* d_out, int out_size, void* d_ws, size_t ws_size,
                              hipStream_t stream)
{
    const float* x    = (const float*)d_in[0];
    const int*   nidx = (const int*)  d_in[1];
    const int*   didx = (const int*)  d_in[2];
    const float* w[7];
    const float* b[7];
    for (int i = 0; i < 7; ++i) {
        w[i] = (const float*)d_in[3 + 2 * i];
        b[i] = (const float*)d_in[4 + 2 * i];
    }

    // Workspace: two ping-pong z buffers in (N, B) layout, 12.8 MB each.
    float* z0 = (float*)d_ws;
    float* z1 = z0 + (size_t)NB * BB;

    const int tblocks = (NB * BB) / 256;   // 12500 (transpose)
    const int pblocks = NB / 8;            // 6250: 4 waves x 2 nodes

    transpose_kernel<<<tblocks, 256, 0, stream>>>(x, z0);

    pass_kernel<<<pblocks, 256, 0, stream>>>(z0, z1, nidx,
        w[0], b[0], w[1], b[1], w[2], b[2], w[3], b[3],
        w[4], b[4], w[5], b[5], w[6], b[6]);
    pass_kernel<<<pblocks, 256, 0, stream>>>(z1, z0, nidx,
        w[0], b[0], w[1], b[1], w[2], b[2], w[3], b[3],
        w[4], b[4], w[5], b[5], w[6], b[6]);
    pass_kernel<<<pblocks, 256, 0, stream>>>(z0, z1, nidx,
        w[0], b[0], w[1], b[1], w[2], b[2], w[3], b[3],
        w[4], b[4], w[5], b[5], w[6], b[6]);
    pass_kernel<<<pblocks, 256, 0, stream>>>(z1, z0, nidx,
        w[0], b[0], w[1], b[1], w[2], b[2], w[3], b[3],
        w[4], b[4], w[5], b[5], w[6], b[6]);

    gather_out_kernel<<<(BB * NDRVN + 255) / 256, 256, 0, stream>>>(z0, didx, (float*)d_out);
}